// Round 10
// baseline (2436.776 us; speedup 1.0000x reference)
//
#include <hip/hip_runtime.h>
#include <hip/hip_fp16.h>

#define B_  16
#define T_  400
#define F_  512
#define U_  1024
#define G4_ 4096
#define NBLK 256

typedef __attribute__((ext_vector_type(8))) short short8;
typedef __attribute__((ext_vector_type(4))) float f32x4;

__device__ __forceinline__ unsigned bf16bits(float f) {
  unsigned u = __float_as_uint(f);
  return (u + 0x7fffu + ((u >> 16) & 1u)) >> 16;   // RNE f32->bf16
}
__device__ __forceinline__ float sigm(float x)   { return 1.f/(1.f + __expf(-x)); }
__device__ __forceinline__ float tanh_f(float x) { return 2.f/(1.f + __expf(-2.f*x)) - 1.f; }

__device__ __forceinline__ void ast(unsigned* p, unsigned v) {
  __hip_atomic_store(p, v, __ATOMIC_RELAXED, __HIP_MEMORY_SCOPE_AGENT);
}
// coherent 16B load (bypass L1/L2 -> coherence point); caller must waitcnt.
__device__ __forceinline__ uint4 ald4(const unsigned* p) {
  uint4 v;
  asm volatile("global_load_dwordx4 %0, %1, off sc0 sc1" : "=v"(v) : "v"(p));
  return v;
}
// pack hi16 of two tagged dwords into one dword (bf16 pair, k then k+1)
__device__ __forceinline__ unsigned pk(unsigned lo_d, unsigned hi_d) {
  return __builtin_amdgcn_perm(hi_d, lo_d, 0x07060302);
}

// ---------------- Persistent bidirectional LSTM, input-GEMM fused --------
// 256 WGs x 256 threads; WG -> (dir = wg>>7, u0 = (wg&127)*8), 32 gate-cols.
// h exchange: SELF-TAGGED dwords hw2[par][dir][b][u] = (bf16(h)<<16)|(s+1);
// sample poll (1 dwordx4/lane covers all 32 quarter-producers), then full
// tag-validated fragment load (r9 structure, proven).
// NEW: xw = x@k+b computed IN-KERNEL by waves 0,1 two steps ahead (LDS ring),
// hidden inside the poll slack. Producers (reduce+h-store) = waves 2,3.
__global__ __launch_bounds__(256, 1) void lstm_rec(
    const float* __restrict__ X,                                   // [16][400][512]
    const float* __restrict__ Kfm, const float* __restrict__ Kbm,  // [512][4096]
    const float* __restrict__ Rf,  const float* __restrict__ Rb,   // [1024][4096]
    const float* __restrict__ Bf,  const float* __restrict__ Bb,   // [4096]
    const float* __restrict__ gammav, const float* __restrict__ betav,
    const float* __restrict__ mmean,  const float* __restrict__ mvar,
    unsigned* __restrict__ hw2,     // [par2][dir2][16][1024] tagged dwords
    float* __restrict__ outp)       // [16][400][2048] f32
{
  __shared__ unsigned short r_bf[32*1040];   // 66560 B  [c][k]  K=1024 recurrent
  __shared__ unsigned short k_s[32*520];     // 33280 B  [c][k]  K=512  input
  __shared__ float z_s[2][4*528];            // 16896 B  [par][wave][16][33]
  __shared__ float ring[4][16*36];           //  9216 B  xw ring [slot][b][c(32)+pad]
  // total 125952 B -> 1 WG/CU

  const int wg  = blockIdx.x;
  const int dir = wg >> 7;
  const int u0  = (wg & 127) * 8;
  const float* R  = dir ? Rb  : Rf;
  const float* Kx = dir ? Kbm : Kfm;
  const float* Bv = dir ? Bb  : Bf;
  const int tid  = threadIdx.x;
  const int wid  = tid >> 6;
  const int lane = tid & 63;

  // ---- stage recurrent weights transposed: r_bf[c][k] = bf16(R[k][gc(c)]) ----
  {
    const int c4 = (tid & 7) * 4;
    const int kb = (tid >> 3) * 32;
    const int gcol = ((c4 >> 3) * U_) + u0 + (c4 & 7);
    for (int kk = 0; kk < 32; ++kk) {
      const float4 rv = *reinterpret_cast<const float4*>(&R[(size_t)(kb+kk)*G4_ + gcol]);
      r_bf[(c4+0)*1040 + kb+kk] = (unsigned short)bf16bits(rv.x);
      r_bf[(c4+1)*1040 + kb+kk] = (unsigned short)bf16bits(rv.y);
      r_bf[(c4+2)*1040 + kb+kk] = (unsigned short)bf16bits(rv.z);
      r_bf[(c4+3)*1040 + kb+kk] = (unsigned short)bf16bits(rv.w);
    }
  }
  // ---- stage input weights transposed: k_s[c][k] = bf16(Kx[k][gc(c)]), K=512 ----
  {
    const int c4 = (tid & 7) * 4;
    const int kb = (tid >> 3) * 16;
    const int gcol = ((c4 >> 3) * U_) + u0 + (c4 & 7);
    for (int kk = 0; kk < 16; ++kk) {
      const float4 kv = *reinterpret_cast<const float4*>(&Kx[(size_t)(kb+kk)*G4_ + gcol]);
      k_s[(c4+0)*520 + kb+kk] = (unsigned short)bf16bits(kv.x);
      k_s[(c4+1)*520 + kb+kk] = (unsigned short)bf16bits(kv.y);
      k_s[(c4+2)*520 + kb+kk] = (unsigned short)bf16bits(kv.z);
      k_s[(c4+3)*520 + kb+kk] = (unsigned short)bf16bits(kv.w);
    }
  }

  // BN constants + bias + cell state live in waves 2,3 (producers)
  float inv = 0.f, add = 0.f, cst = 0.f, bi = 0.f, bfv = 0.f, bgv = 0.f, bov = 0.f;
  const int lt = tid - 128, gb = (lt >> 3) & 15, uu = lt & 7;
  if (tid >= 128) {
    const int j = dir*U_ + u0 + uu;
    inv = gammav[j] * rsqrtf(mvar[j] + 1e-3f);
    add = betav[j] - mmean[j]*inv;
    bi  = Bv[u0 + uu];        bfv = Bv[U_   + u0 + uu];
    bgv = Bv[2*U_ + u0 + uu]; bov = Bv[3*U_ + u0 + uu];
    // h(0) = 0, tag 1, parity 0 (overwrites poison; consumers spin on tags)
    ast(&hw2[(size_t)((0*2 + dir)*16 + gb)*1024 + u0 + uu], 1u);
  }
  __syncthreads();                             // r_bf, k_s staged

  // MFMA fragment addressing + recurrent B-fragment preload (loop-invariant)
  const int arow = lane & 15;                  // A row = batch; B row = col
  const int kgrp = lane >> 4;
  const unsigned short* bc0 = &r_bf[arow*1040 + wid*256];
  const unsigned short* bc1 = &r_bf[(16 + arow)*1040 + wid*256];
  #define LB(P, K) (*reinterpret_cast<const short8*>(&(P)[(K)*32 + kgrp*8]))
  const short8 rb00 = LB(bc0,0), rb01 = LB(bc0,1), rb02 = LB(bc0,2), rb03 = LB(bc0,3);
  const short8 rb04 = LB(bc0,4), rb05 = LB(bc0,5), rb06 = LB(bc0,6), rb07 = LB(bc0,7);
  const short8 rb10 = LB(bc1,0), rb11 = LB(bc1,1), rb12 = LB(bc1,2), rb13 = LB(bc1,3);
  const short8 rb14 = LB(bc1,4), rb15 = LB(bc1,5), rb16 = LB(bc1,6), rb17 = LB(bc1,7);
  #undef LB
  const size_t hfrag_off = (size_t)arow*1024 + wid*256 + kgrp*8;
  const size_t samp_off  = (size_t)((lane >> 5)*8)*1024 + wid*256 + (lane & 31)*8;

  // xw compute for step P (waves 0,1 only): 16-col tile, full K=512
  const unsigned short* kwp = &k_s[(size_t)(wid*16 + arow)*520 + kgrp*8];
  const float* xwp = &X[(size_t)arow*T_*F_ + kgrp*8];
  #define XWCOMP(P)                                                            \
  if (wid < 2 && (P) < T_) {                                                   \
    const int t2 = dir ? (T_-1-(P)) : (P);                                     \
    const float* xp = xwp + (size_t)t2*F_;                                     \
    f32x4 xacc = {0.f,0.f,0.f,0.f};                                            \
    _Pragma("unroll 4")                                                        \
    for (int ks = 0; ks < 16; ++ks) {                                          \
      const float4 xa = *reinterpret_cast<const float4*>(xp + ks*32);          \
      const float4 xb = *reinterpret_cast<const float4*>(xp + ks*32 + 4);      \
      short8 a;                                                                \
      a[0]=(short)bf16bits(xa.x); a[1]=(short)bf16bits(xa.y);                  \
      a[2]=(short)bf16bits(xa.z); a[3]=(short)bf16bits(xa.w);                  \
      a[4]=(short)bf16bits(xb.x); a[5]=(short)bf16bits(xb.y);                  \
      a[6]=(short)bf16bits(xb.z); a[7]=(short)bf16bits(xb.w);                  \
      const short8 b = *reinterpret_cast<const short8*>(kwp + ks*32);          \
      xacc = __builtin_amdgcn_mfma_f32_16x16x32_bf16(a, b, xacc, 0, 0, 0);     \
    }                                                                          \
    float* rw = ring[(P) & 3];                                                 \
    rw[(kgrp*4+0)*36 + wid*16 + arow] = xacc[0];                               \
    rw[(kgrp*4+1)*36 + wid*16 + arow] = xacc[1];                               \
    rw[(kgrp*4+2)*36 + wid*16 + arow] = xacc[2];                               \
    rw[(kgrp*4+3)*36 + wid*16 + arow] = xacc[3];                               \
  }

  XWCOMP(0)
  XWCOMP(1)

  for (int s = 0; s < T_; ++s) {
    const int tin = dir ? (T_-1-s) : s;

    // compute xw two steps ahead (waves 0,1) — hides in the poll slack
    XWCOMP(s + 2)

    const unsigned tgt = (unsigned)(s + 1);
    const size_t pbase = (size_t)((s&1)*2 + dir)*16384;
    #define CK4(Q) (((Q.x&0xffffu)^tgt)|((Q.y&0xffffu)^tgt)|((Q.z&0xffffu)^tgt)|((Q.w&0xffffu)^tgt))

    // cheap sample poll: one dwordx4 per lane, all 32 quarter-producers covered
    {
      const unsigned* sp = hw2 + pbase + samp_off;
      for (;;) {
        const uint4 t = ald4(sp);
        asm volatile("s_waitcnt vmcnt(0)" ::: "memory");
        if (__all((int)(CK4(t) == 0u))) break;
        __builtin_amdgcn_s_sleep(1);
      }
    }

    // full fragment load, tag-validated (expected ~0 retries)
    const unsigned* hgp = hw2 + pbase + hfrag_off;
    uint4 q0,q1,q2,q3,q4,q5,q6,q7,q8,q9,q10,q11,q12,q13,q14,q15;
    for (;;) {
      q0  = ald4(hgp +   0); q1  = ald4(hgp +   4);
      q2  = ald4(hgp +  32); q3  = ald4(hgp +  36);
      q4  = ald4(hgp +  64); q5  = ald4(hgp +  68);
      q6  = ald4(hgp +  96); q7  = ald4(hgp + 100);
      q8  = ald4(hgp + 128); q9  = ald4(hgp + 132);
      q10 = ald4(hgp + 160); q11 = ald4(hgp + 164);
      q12 = ald4(hgp + 192); q13 = ald4(hgp + 196);
      q14 = ald4(hgp + 224); q15 = ald4(hgp + 228);
      asm volatile("s_waitcnt vmcnt(0)" ::: "memory");
      const unsigned mism = CK4(q0)|CK4(q1)|CK4(q2)|CK4(q3)|CK4(q4)|CK4(q5)|CK4(q6)|CK4(q7)
                          | CK4(q8)|CK4(q9)|CK4(q10)|CK4(q11)|CK4(q12)|CK4(q13)|CK4(q14)|CK4(q15);
      if (__all((int)(mism == 0u))) break;
      __builtin_amdgcn_s_sleep(1);
    }
    #undef CK4
    __builtin_amdgcn_sched_barrier(0);

    // unpack + MFMA (8 fragments x 2 col-tiles)
    f32x4 acc0 = {0.f,0.f,0.f,0.f}, acc1 = {0.f,0.f,0.f,0.f};
    #define FRAG(QA, QB, RB0, RB1) { \
      uint4 av; \
      av.x = pk(QA.x, QA.y); av.y = pk(QA.z, QA.w); \
      av.z = pk(QB.x, QB.y); av.w = pk(QB.z, QB.w); \
      const short8 a = *reinterpret_cast<const short8*>(&av); \
      acc0 = __builtin_amdgcn_mfma_f32_16x16x32_bf16(a, RB0, acc0, 0, 0, 0); \
      acc1 = __builtin_amdgcn_mfma_f32_16x16x32_bf16(a, RB1, acc1, 0, 0, 0); }
    FRAG(q0, q1, rb00, rb10) FRAG(q2, q3, rb01, rb11)
    FRAG(q4, q5, rb02, rb12) FRAG(q6, q7, rb03, rb13)
    FRAG(q8, q9, rb04, rb14) FRAG(q10,q11,rb05, rb15)
    FRAG(q12,q13,rb06, rb16) FRAG(q14,q15,rb07, rb17)
    #undef FRAG

    // z partials: D col=lane&15 (gate-col), row=kgrp*4+reg (batch)
    {
      const int col = lane & 15, rbase = kgrp*4;
      float* zw = &z_s[s&1][wid*528];
      #pragma unroll
      for (int r = 0; r < 4; ++r) {
        zw[(rbase+r)*33 + col]      = acc0[r];
        zw[(rbase+r)*33 + 16 + col] = acc1[r];
      }
    }
    __syncthreads();                           // all 4 waves' z(s) complete

    // reduce + gates + tagged h store (fire-and-forget) + outp — waves 2,3
    if (tid >= 128) {
      const float* rg = &ring[s&3][gb*36];
      float zi = rg[uu]      + bi,  zf = rg[8+uu]  + bfv;
      float zg = rg[16+uu]   + bgv, zo = rg[24+uu] + bov;
      #pragma unroll
      for (int w = 0; w < 4; ++w) {
        const float* zr = &z_s[s&1][w*528 + gb*33];
        zi += zr[uu]; zf += zr[8+uu]; zg += zr[16+uu]; zo += zr[24+uu];
      }
      const float ig = sigm(zi), fg = sigm(zf), og = sigm(zo);
      const float gg = tanh_f(zg);
      cst = fg*cst + ig*gg;
      const float hv = og * tanh_f(cst);
      ast(&hw2[(size_t)((((s+1)&1)*2 + dir)*16 + gb)*1024 + u0 + uu],
          (bf16bits(hv) << 16) | (unsigned)(s + 2));
      outp[((size_t)gb*T_ + tin)*2048 + dir*U_ + u0 + uu] = hv*inv + add;
    }
    // no second barrier: z_s parity double-buffered; ring slot reused only
    // after 4 steps (>= 2 barriers separate write and last read)
  }
  #undef XWCOMP
}

extern "C" void kernel_launch(void* const* d_in, const int* in_sizes, int n_in,
                              void* d_out, int out_size, void* d_ws, size_t ws_size,
                              hipStream_t stream)
{
  const float* x  = (const float*)d_in[0];
  const float* kf = (const float*)d_in[1];
  const float* rf = (const float*)d_in[2];
  const float* bf = (const float*)d_in[3];
  const float* kb = (const float*)d_in[4];
  const float* rb = (const float*)d_in[5];
  const float* bb = (const float*)d_in[6];
  const float* ga = (const float*)d_in[7];
  const float* be = (const float*)d_in[8];
  const float* mm = (const float*)d_in[9];
  const float* mv = (const float*)d_in[10];
  float* outp = (float*)d_out;

  // ws: [hw2 tagged dwords 2par*2dir*16*1024*4B = 512KB]
  unsigned* hw2 = (unsigned*)d_ws;

  lstm_rec<<<dim3(NBLK), dim3(256), 0, stream>>>(x, kf, kb, rf, rb, bf, bb,
                                                 ga, be, mm, mv, hw2, outp);
}

// Round 11
// 1827.696 us; speedup vs baseline: 1.3333x; 1.3333x over previous
//
#include <hip/hip_runtime.h>
#include <hip/hip_fp16.h>

#define B_  16
#define T_  400
#define F_  512
#define U_  1024
#define G4_ 4096
#define NBLK 256

typedef __attribute__((ext_vector_type(8))) short short8;
typedef __attribute__((ext_vector_type(4))) float f32x4;

__device__ __forceinline__ unsigned bf16bits(float f) {
  unsigned u = __float_as_uint(f);
  return (u + 0x7fffu + ((u >> 16) & 1u)) >> 16;   // RNE f32->bf16
}
__device__ __forceinline__ float sigm(float x)   { return 1.f/(1.f + __expf(-x)); }
__device__ __forceinline__ float tanh_f(float x) { return 2.f/(1.f + __expf(-2.f*x)) - 1.f; }

__device__ __forceinline__ void ast(unsigned* p, unsigned v) {
  __hip_atomic_store(p, v, __ATOMIC_RELAXED, __HIP_MEMORY_SCOPE_AGENT);
}
// coherent 16B load (bypass L1/L2 -> coherence point); caller must waitcnt.
__device__ __forceinline__ uint4 ald4(const unsigned* p) {
  uint4 v;
  asm volatile("global_load_dwordx4 %0, %1, off sc0 sc1" : "=v"(v) : "v"(p));
  return v;
}

// ---------------- Phase 1: xw[dir] = x @ k_dir + b_dir (MFMA bf16) -------
__global__ __launch_bounds__(256) void gemm_xw(
    const float* __restrict__ X,
    const float* __restrict__ Kf, const float* __restrict__ Kb,
    const float* __restrict__ Bf, const float* __restrict__ Bb,
    __half* __restrict__ xwf, __half* __restrict__ xwb)
{
  const int dir = blockIdx.z;
  const float* Km   = dir ? Kb : Kf;
  const float* bias = dir ? Bb : Bf;
  __half* outp      = dir ? xwb : xwf;
  const int m0 = blockIdx.x * 64;
  const int n0 = blockIdx.y * 64;
  const int tid = threadIdx.x, wid = tid >> 6, lane = tid & 63;

  __shared__ unsigned short A_bf[64*40];
  __shared__ unsigned short B_bf[64*40];

  const int wm = wid >> 1, wn = wid & 1;
  const int arow = lane & 15, kgrp = lane >> 4;
  const int sm = tid & 63, skoct = tid >> 6;

  f32x4 acc00 = {0.f,0.f,0.f,0.f}, acc01 = {0.f,0.f,0.f,0.f};
  f32x4 acc10 = {0.f,0.f,0.f,0.f}, acc11 = {0.f,0.f,0.f,0.f};

  for (int k0 = 0; k0 < F_; k0 += 32) {
    {
      const float* xp = &X[(size_t)(m0+sm)*F_ + k0 + skoct*8];
      const float4 v0 = *reinterpret_cast<const float4*>(xp);
      const float4 v1 = *reinterpret_cast<const float4*>(xp + 4);
      short8 t;
      t[0]=(short)bf16bits(v0.x); t[1]=(short)bf16bits(v0.y);
      t[2]=(short)bf16bits(v0.z); t[3]=(short)bf16bits(v0.w);
      t[4]=(short)bf16bits(v1.x); t[5]=(short)bf16bits(v1.y);
      t[6]=(short)bf16bits(v1.z); t[7]=(short)bf16bits(v1.w);
      *reinterpret_cast<short8*>(&A_bf[sm*40 + skoct*8]) = t;
    }
    {
      short8 t;
      #pragma unroll
      for (int j = 0; j < 8; ++j)
        t[j] = (short)bf16bits(Km[(size_t)(k0+skoct*8+j)*G4_ + n0 + sm]);
      *reinterpret_cast<short8*>(&B_bf[sm*40 + skoct*8]) = t;
    }
    __syncthreads();
    const short8 a0 = *reinterpret_cast<const short8*>(&A_bf[(wm*32 + arow)*40      + kgrp*8]);
    const short8 a1 = *reinterpret_cast<const short8*>(&A_bf[(wm*32 + 16 + arow)*40 + kgrp*8]);
    const short8 b0 = *reinterpret_cast<const short8*>(&B_bf[(wn*32 + arow)*40      + kgrp*8]);
    const short8 b1 = *reinterpret_cast<const short8*>(&B_bf[(wn*32 + 16 + arow)*40 + kgrp*8]);
    acc00 = __builtin_amdgcn_mfma_f32_16x16x32_bf16(a0, b0, acc00, 0, 0, 0);
    acc01 = __builtin_amdgcn_mfma_f32_16x16x32_bf16(a0, b1, acc01, 0, 0, 0);
    acc10 = __builtin_amdgcn_mfma_f32_16x16x32_bf16(a1, b0, acc10, 0, 0, 0);
    acc11 = __builtin_amdgcn_mfma_f32_16x16x32_bf16(a1, b1, acc11, 0, 0, 0);
    __syncthreads();
  }
  #pragma unroll
  for (int tm = 0; tm < 2; ++tm) {
    #pragma unroll
    for (int tn = 0; tn < 2; ++tn) {
      const f32x4 a = tm ? (tn ? acc11 : acc10) : (tn ? acc01 : acc00);
      const int n = n0 + wn*32 + tn*16 + arow;
      const float bv = bias[n];
      #pragma unroll
      for (int r = 0; r < 4; ++r) {
        const int m = m0 + wm*32 + tm*16 + kgrp*4 + r;
        outp[(size_t)m*G4_ + n] = __float2half_rn(a[r] + bv);
      }
    }
  }
}

// ---------------- Phase 2: persistent bidirectional LSTM (MFMA) ----------
// h exchange: PACKED dwords hw2p[par][dir][16][512]: low16=bf16(h_even_u),
// high16=bf16(h_odd_u); TAG = bit0 (mantissa LSB of even-u bf16), expected
// bit at step s = ((s>>1)&1)^1 (alternates between same-parity writes).
// Buffer memset to 0 each launch -> pre-write state always fails the check.
// Loaded uint4 IS the MFMA A-fragment (no unpack). Sample poll (1 dwordx4
// per lane covers all 32 quarter-producers), then full tag-validated load.
__global__ __launch_bounds__(256, 1) void lstm_rec(
    const __half* __restrict__ xwf, const __half* __restrict__ xwb,
    const float* __restrict__ Rf, const float* __restrict__ Rb,
    const float* __restrict__ gammav, const float* __restrict__ betav,
    const float* __restrict__ mmean, const float* __restrict__ mvar,
    unsigned* __restrict__ hw2p,    // [par2][dir2][16][512] packed dwords
    float* __restrict__ outp)       // [16][400][2048] f32
{
  __shared__ unsigned short r_bf[32*1040];     // 66560 B  [c][k] bf16
  __shared__ float z_s[2][4*528];              // 16896 B  [par][wave][16][33]
  // total 83456 B > 80K -> guaranteed 1 WG/CU

  const int wg  = blockIdx.x;
  const int dir = wg >> 7;
  const int u0  = (wg & 127) * 8;
  const __half* xw = dir ? xwb : xwf;
  const float*  R  = dir ? Rb  : Rf;
  const int tid  = threadIdx.x;
  const int wid  = tid >> 6;
  const int lane = tid & 63;

  // stage recurrent weights transposed: r_bf[c][k] = bf16(R[k][gc(c)])
  {
    const int c4 = (tid & 7) * 4;
    const int kb = (tid >> 3) * 32;
    const int gcol = ((c4 >> 3) * U_) + u0 + (c4 & 7);
    for (int kk = 0; kk < 32; ++kk) {
      const float4 rv = *reinterpret_cast<const float4*>(&R[(size_t)(kb+kk)*G4_ + gcol]);
      r_bf[(c4+0)*1040 + kb+kk] = (unsigned short)bf16bits(rv.x);
      r_bf[(c4+1)*1040 + kb+kk] = (unsigned short)bf16bits(rv.y);
      r_bf[(c4+2)*1040 + kb+kk] = (unsigned short)bf16bits(rv.z);
      r_bf[(c4+3)*1040 + kb+kk] = (unsigned short)bf16bits(rv.w);
    }
  }

  float inv = 0.f, add = 0.f, cst = 0.f;
  const int gb = tid >> 3, uu = tid & 7;       // reduce-thread mapping (tid<128)
  if (tid < 128) {
    const int j = dir*U_ + u0 + uu;
    inv = gammav[j] * rsqrtf(mvar[j] + 1e-3f);
    add = betav[j] - mmean[j]*inv;
    // h(0)=0 packed, parity 0, tag bit n=0 -> ((0>>1)&1)^1 = 1
    if (!(uu & 1))
      ast(&hw2p[(size_t)((0*2 + dir)*16 + gb)*512 + (u0 >> 1) + (uu >> 1)], 1u);
  }
  __syncthreads();                             // r_bf staged

  // MFMA fragment addressing + B-fragment preload (registers, loop-invariant)
  const int arow = lane & 15;                  // batch
  const int kgrp = lane >> 4;
  const unsigned short* bc0 = &r_bf[arow*1040 + wid*256];
  const unsigned short* bc1 = &r_bf[(16 + arow)*1040 + wid*256];
  #define LB(P, K) (*reinterpret_cast<const short8*>(&(P)[(K)*32 + kgrp*8]))
  const short8 rb00 = LB(bc0,0), rb01 = LB(bc0,1), rb02 = LB(bc0,2), rb03 = LB(bc0,3);
  const short8 rb04 = LB(bc0,4), rb05 = LB(bc0,5), rb06 = LB(bc0,6), rb07 = LB(bc0,7);
  const short8 rb10 = LB(bc1,0), rb11 = LB(bc1,1), rb12 = LB(bc1,2), rb13 = LB(bc1,3);
  const short8 rb14 = LB(bc1,4), rb15 = LB(bc1,5), rb16 = LB(bc1,6), rb17 = LB(bc1,7);
  #undef LB
  // packed layout: batch row stride 512 dwords; lane's k-chunk ks covers
  // dwords (wid*128 + kgrp*4 + ks*16 .. +4)  (8 k-values = 1 dwordx4)
  const size_t hfrag_off = (size_t)arow*512 + wid*128 + kgrp*4;
  // sample: u-block (lane&31) of this wave's quarter, batch (lane>>5)*8
  const size_t samp_off  = (size_t)((lane >> 5)*8)*512 + wid*128 + (lane & 31)*4;

  for (int s = 0; s < T_; ++s) {
    const int tin = dir ? (T_-1-s) : s;

    // xw prefetch (plain cached loads, issued pre-poll)
    float xv0=0.f, xv1=0.f, xv2=0.f, xv3=0.f;
    if (tid < 128) {
      const __half* xp = &xw[((size_t)gb*T_ + tin)*G4_ + u0 + uu];
      xv0 = __half2float(xp[0]);    xv1 = __half2float(xp[1024]);
      xv2 = __half2float(xp[2048]); xv3 = __half2float(xp[3072]);
    }

    const unsigned eb = (((unsigned)s >> 1) & 1u) ^ 1u;   // expected tag bit
    const size_t pbase = (size_t)((s&1)*2 + dir)*8192;
    #define CKB(Q) (((Q.x ^ eb) | (Q.y ^ eb) | (Q.z ^ eb) | (Q.w ^ eb)) & 1u)

    // cheap sample poll: one dwordx4 per lane, all 32 quarter-producers covered
    {
      const unsigned* sp = hw2p + pbase + samp_off;
      for (;;) {
        const uint4 t = ald4(sp);
        asm volatile("s_waitcnt vmcnt(0)" ::: "memory");
        if (__all((int)(CKB(t) == 0u))) break;
        __builtin_amdgcn_s_sleep(1);
      }
    }

    // full fragment load (8 x dwordx4 = 128B/lane), tag-validated
    const unsigned* hgp = hw2p + pbase + hfrag_off;
    uint4 q0,q1,q2,q3,q4,q5,q6,q7;
    for (;;) {
      q0 = ald4(hgp +  0); q1 = ald4(hgp + 16);
      q2 = ald4(hgp + 32); q3 = ald4(hgp + 48);
      q4 = ald4(hgp + 64); q5 = ald4(hgp + 80);
      q6 = ald4(hgp + 96); q7 = ald4(hgp + 112);
      asm volatile("s_waitcnt vmcnt(0)" ::: "memory");
      const unsigned mism = CKB(q0)|CKB(q1)|CKB(q2)|CKB(q3)
                          | CKB(q4)|CKB(q5)|CKB(q6)|CKB(q7);
      if (__all((int)(mism == 0u))) break;
      __builtin_amdgcn_s_sleep(1);
    }
    #undef CKB
    __builtin_amdgcn_sched_barrier(0);

    // MFMA: loaded uint4 IS the bf16x8 A-fragment (packed pairs in k-order)
    f32x4 acc0 = {0.f,0.f,0.f,0.f}, acc1 = {0.f,0.f,0.f,0.f};
    #define FRAG(Q, RB0, RB1) { \
      const short8 a = *reinterpret_cast<const short8*>(&Q); \
      acc0 = __builtin_amdgcn_mfma_f32_16x16x32_bf16(a, RB0, acc0, 0, 0, 0); \
      acc1 = __builtin_amdgcn_mfma_f32_16x16x32_bf16(a, RB1, acc1, 0, 0, 0); }
    FRAG(q0, rb00, rb10) FRAG(q1, rb01, rb11)
    FRAG(q2, rb02, rb12) FRAG(q3, rb03, rb13)
    FRAG(q4, rb04, rb14) FRAG(q5, rb05, rb15)
    FRAG(q6, rb06, rb16) FRAG(q7, rb07, rb17)
    #undef FRAG

    // z partials: D col=lane&15 (gate-col), row=kgrp*4+reg (batch)
    {
      const int col = lane & 15, rbase = kgrp*4;
      float* zw = &z_s[s&1][wid*528];
      #pragma unroll
      for (int r = 0; r < 4; ++r) {
        zw[(rbase+r)*33 + col]      = acc0[r];
        zw[(rbase+r)*33 + 16 + col] = acc1[r];
      }
    }
    __syncthreads();                           // all 4 waves' z(s) complete

    // reduce + gates + packed tagged h store (fire-and-forget) + outp
    if (tid < 128) {
      float zi = xv0, zf = xv1, zg = xv2, zo = xv3;
      #pragma unroll
      for (int w = 0; w < 4; ++w) {
        const float* zr = &z_s[s&1][w*528 + gb*33];
        zi += zr[uu]; zf += zr[8+uu]; zg += zr[16+uu]; zo += zr[24+uu];
      }
      const float ig = sigm(zi), fg = sigm(zf), og = sigm(zo);
      const float gg = tanh_f(zg);
      cst = fg*cst + ig*gg;
      const float hv = og * tanh_f(cst);
      const unsigned hvb = bf16bits(hv);
      const unsigned hnb = (unsigned)__shfl_down((int)hvb, 1);   // odd-u partner
      if (!(uu & 1)) {
        const unsigned sbit = (((unsigned)(s+1) >> 1) & 1u) ^ 1u;
        const unsigned d = ((hvb & ~1u) | sbit) | (hnb << 16);
        ast(&hw2p[(size_t)((((s+1)&1)*2 + dir)*16 + gb)*512 + (u0 >> 1) + (uu >> 1)], d);
      }
      outp[((size_t)gb*T_ + tin)*2048 + dir*U_ + u0 + uu] = hv*inv + add;
    }
    // no second barrier: z_s parity double-buffered
  }
}

extern "C" void kernel_launch(void* const* d_in, const int* in_sizes, int n_in,
                              void* d_out, int out_size, void* d_ws, size_t ws_size,
                              hipStream_t stream)
{
  const float* x  = (const float*)d_in[0];
  const float* kf = (const float*)d_in[1];
  const float* rf = (const float*)d_in[2];
  const float* bf = (const float*)d_in[3];
  const float* kb = (const float*)d_in[4];
  const float* rb = (const float*)d_in[5];
  const float* bb = (const float*)d_in[6];
  const float* ga = (const float*)d_in[7];
  const float* be = (const float*)d_in[8];
  const float* mm = (const float*)d_in[9];
  const float* mv = (const float*)d_in[10];
  float* outp = (float*)d_out;

  // ws: [hw2p packed 2par*2dir*16*512*4B = 256KB][xwf f16][xwb f16]
  unsigned* hw2p = (unsigned*)d_ws;
  __half* xwf    = (__half*)((char*)d_ws + 262144);
  __half* xwb    = xwf + (size_t)6400*G4_;

  // zero h buffer: memset-0 always fails the tag check (bit0=0 vs expected 1
  // at s=0), eliminating cross-replay stale-tag collisions for the 1-bit tag
  hipMemsetAsync(hw2p, 0, 262144, stream);
  gemm_xw<<<dim3(100, 64, 2), dim3(256), 0, stream>>>(x, kf, kb, bf, bb, xwf, xwb);
  lstm_rec<<<dim3(NBLK), dim3(256), 0, stream>>>(xwf, xwb, rf, rb, ga, be, mm, mv,
                                                 hw2p, outp);
}